// Round 1
// baseline (178.476 us; speedup 1.0000x reference)
//
#include <hip/hip_runtime.h>
#include <float.h>
#include <stdint.h>

// Problem constants
#define BATCHES 32
#define P 1024
#define KNN 16
#define C 64
#define H 128
#define N (BATCHES * P)   // 32768
#define NCOLS 384         // U(128) | V(128) | S(128)

typedef short short8 __attribute__((ext_vector_type(8)));
typedef float floatx4 __attribute__((ext_vector_type(4)));

__device__ __forceinline__ unsigned short f2bf(float f) {
    unsigned u = __float_as_uint(f);
    unsigned r = (u + 0x7FFF + ((u >> 16) & 1)) >> 16;   // RNE
    return (unsigned short)r;
}

// ---------------------------------------------------------------------------
// prep_w: build WcatT (bf16, [384][64]) and bias_cat (fp32, [384])
//   col <128  : Wu = W_e[0:64] - W_e[64:128], bias = b_e
//   col <256  : B  = W_e[64:128],             bias = 0
//   col <384  : W_sc,                         bias = b_sc
// ---------------------------------------------------------------------------
__global__ __launch_bounds__(256) void prep_w(
    const float* __restrict__ W_e, const float* __restrict__ b_e,
    const float* __restrict__ W_sc, const float* __restrict__ b_sc,
    unsigned short* __restrict__ WT, float* __restrict__ bias)
{
    int i = blockIdx.x * 256 + threadIdx.x;      // 0 .. 384*64-1
    int col = i >> 6, c = i & 63;
    float w;
    if (col < 128)      w = W_e[c * 128 + col] - W_e[(64 + c) * 128 + col];
    else if (col < 256) w = W_e[(64 + c) * 128 + (col - 128)];
    else                w = W_sc[c * 128 + (col - 256)];
    WT[col * 64 + c] = f2bf(w);
    if (c == 0) {
        bias[col] = (col < 128) ? b_e[col] : (col < 256 ? 0.0f : b_sc[col - 256]);
    }
}

// ---------------------------------------------------------------------------
// prep_x: X fp32 -> bf16 (row-major N x 64)
// ---------------------------------------------------------------------------
__global__ __launch_bounds__(256) void prep_x(
    const float* __restrict__ X, unsigned short* __restrict__ Xb)
{
    int i = blockIdx.x * 256 + threadIdx.x;      // one float4 per thread
    float4 v = ((const float4*)X)[i];
    uint64_t pk = (uint64_t)f2bf(v.x) | ((uint64_t)f2bf(v.y) << 16) |
                  ((uint64_t)f2bf(v.z) << 32) | ((uint64_t)f2bf(v.w) << 48);
    ((uint64_t*)Xb)[i] = pk;
}

// ---------------------------------------------------------------------------
// knn: exact top-16 per point (within batch), matching the reference formula
//      d2 = sq_i + sq_j - 2*dot  computed with non-contractible fp32 ops.
// Block: 256 threads = 64 queries x 4 candidate-splits (wave s scans
// candidates [s*256,(s+1)*256) -- all lanes of a wave read the same spos[j]
// => LDS broadcast). Phase A: value-only sorted-16 via v_med3 ladder.
// Merge -> exact 16th smallest T. Phase B: emit j with d2 <= T ascending.
// ---------------------------------------------------------------------------
__global__ __launch_bounds__(256) void knn_kernel(
    const float* __restrict__ pos, int* __restrict__ idx_out)
{
    int t = threadIdx.x;
    int q = t & 63, s = t >> 6;                  // s == wave id
    int batch = blockIdx.x >> 4;                 // 16 blocks per batch
    int qblk  = blockIdx.x & 15;
    int iloc  = qblk * 64 + q;                   // query local index in batch

    __shared__ float4 spos[P];                   // x,y,z,sq
    __shared__ float  lists[64][4][16];
    __shared__ int    elist[64][4][16];
    __shared__ int    ecnt[64][4];
    __shared__ float  Tq[64];

    const float* pb = pos + (size_t)batch * P * 3;
    for (int j = t; j < P; j += 256) {
        float x = pb[j * 3 + 0], y = pb[j * 3 + 1], z = pb[j * 3 + 2];
        float sq = __fadd_rn(__fadd_rn(__fmul_rn(x, x), __fmul_rn(y, y)),
                             __fmul_rn(z, z));
        spos[j] = make_float4(x, y, z, sq);
    }
    __syncthreads();

    float4 me = spos[iloc];
    float d[16];
#pragma unroll
    for (int k = 0; k < 16; ++k) d[k] = FLT_MAX;

    const int j0 = s * 256;
    // ---- Phase A: smallest 16 values of this split ----
    for (int jj = 0; jj < 256; ++jj) {
        int j = j0 + jj;
        float4 c = spos[j];
        float dot = __fadd_rn(__fadd_rn(__fmul_rn(me.x, c.x), __fmul_rn(me.y, c.y)),
                              __fmul_rn(me.z, c.z));
        float d2 = __fadd_rn(__fadd_rn(me.w, c.w), __fmul_rn(-2.0f, dot));
        if (j == iloc) d2 = FLT_MAX;
        if (d2 < d[15]) {
            // branchless sorted insert: d[t] = clamp(d2, d[t-1], d[t]) = med3
#pragma unroll
            for (int k = 15; k >= 1; --k)
                d[k] = __builtin_amdgcn_fmed3f(d[k - 1], d2, d[k]);
            d[0] = fminf(d[0], d2);
        }
    }
#pragma unroll
    for (int k = 0; k < 16; ++k) lists[q][s][k] = d[k];
    __syncthreads();

    // ---- merge 4 sorted lists -> exact global 16th smallest (wave 0) ----
    if (s == 0) {
        int p0 = 0, p1 = 0, p2 = 0, p3 = 0;
        float T = 0.0f;
        for (int k = 0; k < 16; ++k) {
            float v0 = lists[q][0][p0], v1 = lists[q][1][p1];
            float v2 = lists[q][2][p2], v3 = lists[q][3][p3];
            float mn = fminf(fminf(v0, v1), fminf(v2, v3));
            if      (v0 == mn) p0++;
            else if (v1 == mn) p1++;
            else if (v2 == mn) p2++;
            else               p3++;
            T = mn;
        }
        Tq[q] = T;
    }
    __syncthreads();
    float T = Tq[q];

    // ---- Phase B: emit indices with d2 <= T, ascending j ----
    int cnt = 0;
    for (int jj = 0; jj < 256; ++jj) {
        int j = j0 + jj;
        float4 c = spos[j];
        float dot = __fadd_rn(__fadd_rn(__fmul_rn(me.x, c.x), __fmul_rn(me.y, c.y)),
                              __fmul_rn(me.z, c.z));
        float d2 = __fadd_rn(__fadd_rn(me.w, c.w), __fmul_rn(-2.0f, dot));
        if (j == iloc) d2 = FLT_MAX;
        if (d2 <= T && cnt < 16) {
            elist[q][s][cnt] = j;
            cnt++;
        }
    }
    ecnt[q][s] = cnt;
    __syncthreads();

    if (s == 0) {
        int out = 0;
        int gbase = (batch * P + iloc) * KNN;
        for (int ss = 0; ss < 4; ++ss) {
            int cc = ecnt[q][ss];
            for (int k = 0; k < cc && out < KNN; ++k) {
                idx_out[gbase + out] = batch * P + elist[q][ss][k];
                out++;
            }
        }
    }
}

// ---------------------------------------------------------------------------
// gemm: Xb (bf16, N x 64) @ WcatT (bf16, 384 x 64, row=col-of-output)
//   -> U (N x 128), V (N x 128), S -> d_out (N x 128), fp32, + bias_cat
// One wave per 16-row m-tile; the wave sweeps all 24 n-tiles of 16 cols.
// mfma_f32_16x16x32_bf16: A[m=lane&15][k=(lane>>4)*8+j], B likewise on W^T,
// C/D: col=lane&15, row=(lane>>4)*4+reg.
// ---------------------------------------------------------------------------
__global__ __launch_bounds__(256) void gemm_kernel(
    const unsigned short* __restrict__ Xb, const unsigned short* __restrict__ WT,
    const float* __restrict__ bias,
    float* __restrict__ U, float* __restrict__ V, float* __restrict__ S)
{
    int t = threadIdx.x;
    int wave = t >> 6, l = t & 63;
    int m0 = (blockIdx.x * 4 + wave) * 16;
    int lm = l & 15, kg = l >> 4;

    const short8* arow = (const short8*)(Xb + (size_t)(m0 + lm) * 64 + kg * 8);
    short8 a0 = arow[0];
    short8 a1 = arow[4];   // +32 bf16

#pragma unroll 4
    for (int nt = 0; nt < 24; ++nt) {
        const short8* brow = (const short8*)(WT + (size_t)(nt * 16 + lm) * 64 + kg * 8);
        short8 b0 = brow[0];
        short8 b1 = brow[4];
        floatx4 acc = {0.0f, 0.0f, 0.0f, 0.0f};
        acc = __builtin_amdgcn_mfma_f32_16x16x32_bf16(a0, b0, acc, 0, 0, 0);
        acc = __builtin_amdgcn_mfma_f32_16x16x32_bf16(a1, b1, acc, 0, 0, 0);

        int col = nt * 16 + lm;
        float bv = bias[col];
        float* dst; int cl;
        if (col < 128)      { dst = U; cl = col; }
        else if (col < 256) { dst = V; cl = col - 128; }
        else                { dst = S; cl = col - 256; }
#pragma unroll
        for (int r = 0; r < 4; ++r) {
            int row = m0 + kg * 4 + r;
            dst[(size_t)row * H + cl] = acc[r] + bv;
        }
    }
}

// ---------------------------------------------------------------------------
// final: out[p][h] = relu(U[p][h] + max_j V[nbr_j][h]) + S[p][h]
// (S already resides in d_out). Block = 2 points x 128 h-threads.
// ---------------------------------------------------------------------------
__global__ __launch_bounds__(256) void final_kernel(
    const int* __restrict__ idx, const float* __restrict__ U,
    const float* __restrict__ V, float* __restrict__ out)
{
    int t = threadIdx.x;
    int pin = t >> 7, h = t & 127;
    size_t p = (size_t)blockIdx.x * 2 + pin;

    __shared__ int nbr[2][KNN];
    if (h < KNN) nbr[pin][h] = idx[p * KNN + h];
    __syncthreads();

    float u = U[p * H + h];
    float m = -FLT_MAX;
#pragma unroll
    for (int k = 0; k < KNN; ++k)
        m = fmaxf(m, V[(size_t)nbr[pin][k] * H + h]);

    float sv = out[p * H + h];
    out[p * H + h] = fmaxf(u + m, 0.0f) + sv;
}

// ---------------------------------------------------------------------------
extern "C" void kernel_launch(void* const* d_in, const int* in_sizes, int n_in,
                              void* d_out, int out_size, void* d_ws, size_t ws_size,
                              hipStream_t stream)
{
    const float* x    = (const float*)d_in[0];
    const float* pos  = (const float*)d_in[1];
    // d_in[2] = batch indices (implicit: i / P) -- unused
    const float* W_e  = (const float*)d_in[3];
    const float* b_e  = (const float*)d_in[4];
    const float* W_sc = (const float*)d_in[5];
    const float* b_sc = (const float*)d_in[6];
    float* out = (float*)d_out;

    char* ws = (char*)d_ws;
    // workspace layout (bytes)
    const size_t OFF_IDX  = 0;                          // N*K*4      = 2 MB
    const size_t OFF_U    = 2ull << 20;                 // N*H*4      = 16 MB
    const size_t OFF_V    = OFF_U + (16ull << 20);      // 16 MB
    const size_t OFF_XB   = OFF_V + (16ull << 20);      // N*C*2      = 4 MB
    const size_t OFF_WT   = OFF_XB + (4ull << 20);      // 384*64*2   = 48 KB
    const size_t OFF_BIAS = OFF_WT + (64ull << 10);     // 384*4

    int*            idx  = (int*)(ws + OFF_IDX);
    float*          U    = (float*)(ws + OFF_U);
    float*          V    = (float*)(ws + OFF_V);
    unsigned short* Xb   = (unsigned short*)(ws + OFF_XB);
    unsigned short* WT   = (unsigned short*)(ws + OFF_WT);
    float*          bias = (float*)(ws + OFF_BIAS);

    prep_w<<<(NCOLS * C) / 256, 256, 0, stream>>>(W_e, b_e, W_sc, b_sc, WT, bias);
    prep_x<<<(N * C / 4) / 256, 256, 0, stream>>>(x, Xb);
    knn_kernel<<<BATCHES * 16, 256, 0, stream>>>(pos, idx);
    gemm_kernel<<<(N / 16) / 4, 256, 0, stream>>>(Xb, WT, bias, U, V, out);
    final_kernel<<<N / 2, 256, 0, stream>>>(idx, U, V, out);
}

// Round 2
// 151.967 us; speedup vs baseline: 1.1744x; 1.1744x over previous
//
#include <hip/hip_runtime.h>
#include <float.h>
#include <stdint.h>

// Problem constants
#define BATCHES 32
#define P 1024
#define KNN 16
#define C 64
#define H 128
#define N (BATCHES * P)   // 32768
#define NCOLS 384         // U(128) | V(128) | S(128)
#define SPLITS 8
#define CPS 128           // candidates per split (P / SPLITS)

typedef short short8 __attribute__((ext_vector_type(8)));
typedef float floatx4 __attribute__((ext_vector_type(4)));

__device__ __forceinline__ unsigned short f2bf(float f) {
    unsigned u = __float_as_uint(f);
    unsigned r = (u + 0x7FFF + ((u >> 16) & 1)) >> 16;   // RNE
    return (unsigned short)r;
}

// ---------------------------------------------------------------------------
// prep_w: build WcatT (bf16, [384][64]) and bias_cat (fp32, [384])
//   col <128  : Wu = W_e[0:64] - W_e[64:128], bias = b_e
//   col <256  : B  = W_e[64:128],             bias = 0
//   col <384  : W_sc,                         bias = b_sc
// ---------------------------------------------------------------------------
__global__ __launch_bounds__(256) void prep_w(
    const float* __restrict__ W_e, const float* __restrict__ b_e,
    const float* __restrict__ W_sc, const float* __restrict__ b_sc,
    unsigned short* __restrict__ WT, float* __restrict__ bias)
{
    int i = blockIdx.x * 256 + threadIdx.x;      // 0 .. 384*64-1
    int col = i >> 6, c = i & 63;
    float w;
    if (col < 128)      w = W_e[c * 128 + col] - W_e[(64 + c) * 128 + col];
    else if (col < 256) w = W_e[(64 + c) * 128 + (col - 128)];
    else                w = W_sc[c * 128 + (col - 256)];
    WT[col * 64 + c] = f2bf(w);
    if (c == 0) {
        bias[col] = (col < 128) ? b_e[col] : (col < 256 ? 0.0f : b_sc[col - 256]);
    }
}

// ---------------------------------------------------------------------------
// knn: exact top-16 per point (within batch), bit-identical distance formula
// to the round-1 passing version: d2 = sq_i + sq_j - 2*dot, non-contractible.
// Block: 512 threads = 64 queries (lanes) x 8 waves (candidate splits of 128).
// Phase A: UNconditional med3 sorted-16 ladder (wave divergence made the
// conditional version always-taken anyway). lists/elist are lane-stride-1
// (round 1 had 64-way bank conflicts: 1.05M SQ_LDS_BANK_CONFLICT).
// Merge: 8-way pointer merge -> exact 16th-smallest T.
// Phase B: emit local j with d2 <= T ascending per split; concat in split
// order (= ascending j), identical tie semantics to round 1.
// ---------------------------------------------------------------------------
__global__ __launch_bounds__(512) void knn_kernel(
    const float* __restrict__ pos, int* __restrict__ idx_out)
{
    int t = threadIdx.x;
    int q = t & 63, s = t >> 6;                  // s == wave id == split
    int batch = blockIdx.x >> 4;                 // 16 blocks per batch
    int qblk  = blockIdx.x & 15;
    int iloc  = qblk * 64 + q;                   // query local index in batch

    __shared__ float4 spos[P];                           // 16 KB
    __shared__ float  lists[SPLITS][16][64];             // 32 KB, lane-stride 1
    __shared__ unsigned short elist[SPLITS][16][64];     // 16 KB
    __shared__ int    ecnt[SPLITS][64];                  // 2 KB
    __shared__ float  Tq[64];

    const float* pb = pos + (size_t)batch * P * 3;
    for (int j = t; j < P; j += 512) {
        float x = pb[j * 3 + 0], y = pb[j * 3 + 1], z = pb[j * 3 + 2];
        float sq = __fadd_rn(__fadd_rn(__fmul_rn(x, x), __fmul_rn(y, y)),
                             __fmul_rn(z, z));
        spos[j] = make_float4(x, y, z, sq);
    }
    __syncthreads();

    float4 me = spos[iloc];
    float d[16];
#pragma unroll
    for (int k = 0; k < 16; ++k) d[k] = FLT_MAX;

    const int j0 = s * CPS;
    // ---- Phase A: smallest 16 values of this split (unconditional ladder) --
    for (int jj = 0; jj < CPS; ++jj) {
        int j = j0 + jj;
        float4 c = spos[j];
        float dot = __fadd_rn(__fadd_rn(__fmul_rn(me.x, c.x), __fmul_rn(me.y, c.y)),
                              __fmul_rn(me.z, c.z));
        float d2 = __fadd_rn(__fadd_rn(me.w, c.w), __fmul_rn(-2.0f, dot));
        if (j == iloc) d2 = FLT_MAX;
        // branchless sorted insert: d[k] = med3(d[k-1], d2, d[k])
#pragma unroll
        for (int k = 15; k >= 1; --k)
            d[k] = __builtin_amdgcn_fmed3f(d[k - 1], d2, d[k]);
        d[0] = fminf(d[0], d2);
    }
#pragma unroll
    for (int k = 0; k < 16; ++k) lists[s][k][q] = d[k];
    __syncthreads();

    // ---- merge 8 sorted lists -> exact global 16th smallest (wave 0) ----
    if (s == 0) {
        float v0 = lists[0][0][q], v1 = lists[1][0][q];
        float v2 = lists[2][0][q], v3 = lists[3][0][q];
        float v4 = lists[4][0][q], v5 = lists[5][0][q];
        float v6 = lists[6][0][q], v7 = lists[7][0][q];
        int p0 = 0, p1 = 0, p2 = 0, p3 = 0, p4 = 0, p5 = 0, p6 = 0, p7 = 0;
        float T = 0.0f;
        for (int k = 0; k < 16; ++k) {
            float mn = fminf(fminf(fminf(v0, v1), fminf(v2, v3)),
                             fminf(fminf(v4, v5), fminf(v6, v7)));
            if      (v0 == mn) { p0++; v0 = (p0 < 16) ? lists[0][p0][q] : FLT_MAX; }
            else if (v1 == mn) { p1++; v1 = (p1 < 16) ? lists[1][p1][q] : FLT_MAX; }
            else if (v2 == mn) { p2++; v2 = (p2 < 16) ? lists[2][p2][q] : FLT_MAX; }
            else if (v3 == mn) { p3++; v3 = (p3 < 16) ? lists[3][p3][q] : FLT_MAX; }
            else if (v4 == mn) { p4++; v4 = (p4 < 16) ? lists[4][p4][q] : FLT_MAX; }
            else if (v5 == mn) { p5++; v5 = (p5 < 16) ? lists[5][p5][q] : FLT_MAX; }
            else if (v6 == mn) { p6++; v6 = (p6 < 16) ? lists[6][p6][q] : FLT_MAX; }
            else               { p7++; v7 = (p7 < 16) ? lists[7][p7][q] : FLT_MAX; }
            T = mn;
        }
        Tq[q] = T;
    }
    __syncthreads();
    float T = Tq[q];

    // ---- Phase B: emit local indices with d2 <= T, ascending j ----
    int cnt = 0;
    for (int jj = 0; jj < CPS; ++jj) {
        int j = j0 + jj;
        float4 c = spos[j];
        float dot = __fadd_rn(__fadd_rn(__fmul_rn(me.x, c.x), __fmul_rn(me.y, c.y)),
                              __fmul_rn(me.z, c.z));
        float d2 = __fadd_rn(__fadd_rn(me.w, c.w), __fmul_rn(-2.0f, dot));
        if (j == iloc) d2 = FLT_MAX;
        if (d2 <= T && cnt < 16) {
            elist[s][cnt][q] = (unsigned short)j;
            cnt++;
        }
    }
    ecnt[s][q] = cnt;
    __syncthreads();

    if (s == 0) {
        int out = 0;
        int gbase = (batch * P + iloc) * KNN;
        int base  = batch * P;
        for (int ss = 0; ss < SPLITS; ++ss) {
            int cc = ecnt[ss][q];
            for (int k = 0; k < cc && out < KNN; ++k) {
                idx_out[gbase + out] = base + (int)elist[ss][k][q];
                out++;
            }
        }
    }
}

// ---------------------------------------------------------------------------
// gemm: x (fp32, N x 64, converted inline to bf16) @ WcatT (bf16, 384 x 64)
//   -> U, V, S (bf16, N x 128 each) + bias_cat
// One wave per 16-row m-tile; sweeps all 24 n-tiles of 16 cols.
// mfma_f32_16x16x32_bf16; C/D: col=lane&15, row=(lane>>4)*4+reg.
// ---------------------------------------------------------------------------
__global__ __launch_bounds__(256) void gemm_kernel(
    const float* __restrict__ X, const unsigned short* __restrict__ WT,
    const float* __restrict__ bias,
    unsigned short* __restrict__ U, unsigned short* __restrict__ V,
    unsigned short* __restrict__ S)
{
    int t = threadIdx.x;
    int wave = t >> 6, l = t & 63;
    int m0 = (blockIdx.x * 4 + wave) * 16;
    int lm = l & 15, kg = l >> 4;

    // A fragment: row m0+lm, k = kg*8..+8 (frag0) and 32+kg*8..+8 (frag1)
    const float4* arow = (const float4*)(X + (size_t)(m0 + lm) * 64 + kg * 8);
    float4 f0 = arow[0], f1 = arow[1];           // k = kg*8 .. +8
    float4 f2 = arow[8], f3 = arow[9];           // k = 32+kg*8 .. +8
    short8 a0, a1;
    a0[0] = (short)f2bf(f0.x); a0[1] = (short)f2bf(f0.y);
    a0[2] = (short)f2bf(f0.z); a0[3] = (short)f2bf(f0.w);
    a0[4] = (short)f2bf(f1.x); a0[5] = (short)f2bf(f1.y);
    a0[6] = (short)f2bf(f1.z); a0[7] = (short)f2bf(f1.w);
    a1[0] = (short)f2bf(f2.x); a1[1] = (short)f2bf(f2.y);
    a1[2] = (short)f2bf(f2.z); a1[3] = (short)f2bf(f2.w);
    a1[4] = (short)f2bf(f3.x); a1[5] = (short)f2bf(f3.y);
    a1[6] = (short)f2bf(f3.z); a1[7] = (short)f2bf(f3.w);

#pragma unroll 4
    for (int nt = 0; nt < 24; ++nt) {
        const short8* brow = (const short8*)(WT + (size_t)(nt * 16 + lm) * 64 + kg * 8);
        short8 b0 = brow[0];
        short8 b1 = brow[4];
        floatx4 acc = {0.0f, 0.0f, 0.0f, 0.0f};
        acc = __builtin_amdgcn_mfma_f32_16x16x32_bf16(a0, b0, acc, 0, 0, 0);
        acc = __builtin_amdgcn_mfma_f32_16x16x32_bf16(a1, b1, acc, 0, 0, 0);

        int col = nt * 16 + lm;
        float bv = bias[col];
        unsigned short* dst; int cl;
        if (col < 128)      { dst = U; cl = col; }
        else if (col < 256) { dst = V; cl = col - 128; }
        else                { dst = S; cl = col - 256; }
#pragma unroll
        for (int r = 0; r < 4; ++r) {
            int row = m0 + kg * 4 + r;
            dst[(size_t)row * H + cl] = f2bf(acc[r] + bv);
        }
    }
}

// ---------------------------------------------------------------------------
// final: out[p][h] = relu(U[p][h] + max_j V[nbr_j][h]) + S[p][h]  (write-only)
// Block = 4 points x 64 lanes; each lane handles 2 cols via packed uint.
// ---------------------------------------------------------------------------
__global__ __launch_bounds__(256) void final_kernel(
    const int* __restrict__ idx, const unsigned short* __restrict__ U,
    const unsigned short* __restrict__ V, const unsigned short* __restrict__ S,
    float* __restrict__ out)
{
    int t = threadIdx.x;
    int pin = t >> 6, c = t & 63;                // c -> cols 2c, 2c+1
    size_t p = (size_t)blockIdx.x * 4 + pin;

    __shared__ int nbr[4][KNN];
    if (t < 64) nbr[t >> 4][t & 15] = idx[(size_t)blockIdx.x * 4 * KNN + t];
    __syncthreads();

    unsigned uu = ((const unsigned*)(U + p * H))[c];
    unsigned ss = ((const unsigned*)(S + p * H))[c];
    float u0 = __uint_as_float(uu << 16);
    float u1 = __uint_as_float(uu & 0xFFFF0000u);
    float s0 = __uint_as_float(ss << 16);
    float s1 = __uint_as_float(ss & 0xFFFF0000u);

    float m0 = -FLT_MAX, m1 = -FLT_MAX;
#pragma unroll
    for (int k = 0; k < KNN; ++k) {
        unsigned vv = ((const unsigned*)(V + (size_t)nbr[pin][k] * H))[c];
        m0 = fmaxf(m0, __uint_as_float(vv << 16));
        m1 = fmaxf(m1, __uint_as_float(vv & 0xFFFF0000u));
    }

    float2 o;
    o.x = fmaxf(u0 + m0, 0.0f) + s0;
    o.y = fmaxf(u1 + m1, 0.0f) + s1;
    ((float2*)(out + p * H))[c] = o;
}

// ---------------------------------------------------------------------------
extern "C" void kernel_launch(void* const* d_in, const int* in_sizes, int n_in,
                              void* d_out, int out_size, void* d_ws, size_t ws_size,
                              hipStream_t stream)
{
    const float* x    = (const float*)d_in[0];
    const float* pos  = (const float*)d_in[1];
    // d_in[2] = batch indices (implicit: i / P) -- unused
    const float* W_e  = (const float*)d_in[3];
    const float* b_e  = (const float*)d_in[4];
    const float* W_sc = (const float*)d_in[5];
    const float* b_sc = (const float*)d_in[6];
    float* out = (float*)d_out;

    char* ws = (char*)d_ws;
    // workspace layout (bytes)
    const size_t OFF_IDX  = 0;                          // N*K*4      = 2 MB
    const size_t OFF_U    = 2ull << 20;                 // N*H*2      = 8 MB
    const size_t OFF_V    = OFF_U + (8ull << 20);       // 8 MB
    const size_t OFF_S    = OFF_V + (8ull << 20);       // 8 MB
    const size_t OFF_WT   = OFF_S + (8ull << 20);       // 384*64*2   = 48 KB
    const size_t OFF_BIAS = OFF_WT + (64ull << 10);     // 384*4

    int*            idx  = (int*)(ws + OFF_IDX);
    unsigned short* U    = (unsigned short*)(ws + OFF_U);
    unsigned short* V    = (unsigned short*)(ws + OFF_V);
    unsigned short* S    = (unsigned short*)(ws + OFF_S);
    unsigned short* WT   = (unsigned short*)(ws + OFF_WT);
    float*          bias = (float*)(ws + OFF_BIAS);

    prep_w<<<(NCOLS * C) / 256, 256, 0, stream>>>(W_e, b_e, W_sc, b_sc, WT, bias);
    knn_kernel<<<BATCHES * 16, 512, 0, stream>>>(pos, idx);
    gemm_kernel<<<(N / 16) / 4, 256, 0, stream>>>(x, WT, bias, U, V, S);
    final_kernel<<<N / 4, 256, 0, stream>>>(idx, U, V, S, out);
}